// Round 3
// baseline (94.463 us; speedup 1.0000x reference)
//
#include <hip/hip_runtime.h>
#include <hip/hip_fp16.h>
#include <math.h>

// StripePolynomial2d, round 9: MEASUREMENT PROBE (not an optimization).
// R7 (occupancy x2, fusion, prefetch) and R8 (VALU -35% via fma_mix) were both
// null -> kernel is not occupancy/latency/VALU-bound. Hypotheses:
//   A: kernel ~10-12us (at LDS/HBM pipe floor), dur_us dominated by harness
//      reset (44.5us ws-fill + ~4us out-fill + ~20-25us of tiny memsets).
//   B: kernel ~35us via an unidentified mechanism.
// This probe runs the IDENTICAL computation twice (grid-stride over 2*NTILE,
// second pass re-stores bit-identical values -> output unchanged). The dur_us
// delta vs R8 directly measures one compute pass (pass-2 x loads are L3-warm):
//   A -> dur_us ~93-97;  B -> dur_us ~110-120.
// Inner loop/table/layout identical to R8.

#define NREC 576              // 9 ec * 64 seg
#define NTILE 8192            // 8 imgs * 1024 tiles
#define NBLK 1024

__device__ __forceinline__ __half2 u2h2(unsigned int u) {
    __half2 h; __builtin_memcpy(&h, &u, 4); return h;
}
__device__ __forceinline__ unsigned int h22u(__half2 h) {
    unsigned int u; __builtin_memcpy(&u, &h, 4); return u;
}

// D.f32 = cvt(f16) * f32 + cvt(f16)  -- exact cvt, f32 fma.
#define FMAMIX_T_LL(d, a, xl, b) \
    asm("v_fma_mix_f32 %0, %1, %2, %3 op_sel_hi:[1,0,1]" \
        : "=v"(d) : "v"(a), "v"(xl), "v"(b))
#define FMAMIX_T_HH(d, a, xl, b) \
    asm("v_fma_mix_f32 %0, %1, %2, %3 op_sel:[1,0,1] op_sel_hi:[1,0,1]" \
        : "=v"(d) : "v"(a), "v"(xl), "v"(b))
#define FMAMIX_T_LH(d, a, xl, b) \
    asm("v_fma_mix_f32 %0, %1, %2, %3 op_sel:[0,0,1] op_sel_hi:[1,0,1]" \
        : "=v"(d) : "v"(a), "v"(xl), "v"(b))
#define FMAMIX_U_L(d, t, xl, b) \
    asm("v_fma_mix_f32 %0, %1, %2, %3 op_sel_hi:[0,0,1]" \
        : "=v"(d) : "v"(t), "v"(xl), "v"(b))
#define FMAMIX_U_H(d, t, xl, b) \
    asm("v_fma_mix_f32 %0, %1, %2, %3 op_sel:[0,0,1] op_sel_hi:[0,0,1]" \
        : "=v"(d) : "v"(t), "v"(xl), "v"(b))

__device__ __forceinline__ void coeff_compute(const float* __restrict__ Wt, int r,
                                              unsigned int rec[8]) {
    int ec  = r >> 6;
    int seg = r & 63;
    int e   = ec / 3;
    int c   = ec - e * 3;
    int nb  = 2 * seg;
    float c0[3], c1[3], c2[3];
    #pragma unroll
    for (int o = 0; o < 3; ++o) {
        float w0, w1, w2;
        if (e == 0) {
            const float* p0 = Wt + ((0 * 3 + o) * 3 + c) * 129 + nb;
            const float* p1 = Wt + ((1 * 3 + o) * 3 + c) * 129 + nb;
            w0 = p0[0] + p1[0]; w1 = p0[1] + p1[1]; w2 = p0[2] + p1[2];
        } else {
            const float* p = Wt + (((e + 1) * 3 + o) * 3 + c) * 129 + nb;
            w0 = p[0]; w1 = p[1]; w2 = p[2];
        }
        c0[o] = 0.25f  * w1;
        c1[o] = 0.125f * (w2 - w0);
        c2[o] = 0.125f * (w0 + w2) - 0.25f * w1;
    }
    rec[0] = h22u(__floats2half2_rn(c0[0], c0[1]));
    rec[1] = h22u(__floats2half2_rn(c1[0], c1[1]));
    rec[2] = h22u(__floats2half2_rn(c2[0], c2[1]));
    rec[3] = h22u(__floats2half2_rn(c0[2], c1[2]));
    rec[4] = h22u(__floats2half2_rn(c2[2], 0.0f));
    rec[5] = 0u; rec[6] = 0u; rec[7] = 0u;
}

__global__ __launch_bounds__(256, 4) void stripe_all(
    const float* __restrict__ x, const float* __restrict__ Wt,
    float* __restrict__ out)
{
    __shared__ uint4 lw4[NREC * 2];   // 18432 B
    const unsigned int* lw = (const unsigned int*)lw4;
    const int tid = threadIdx.x;

    // ---- prefetch first tile's x while the table is being built ----
    const int t0 = blockIdx.x;
    float pf[3];
    {
        const int b  = t0 >> 10;
        const int p  = ((t0 & 1023) << 8) + tid;
        const int xb = ((b * 3) << 18) + p;
        pf[0] = x[xb];
        pf[1] = x[xb + (1 << 18)];
        pf[2] = x[xb + (2 << 18)];
    }

    // ---- build coeff table once per block ----
    for (int r = tid; r < NREC; r += 256) {
        unsigned int rec[8];
        coeff_compute(Wt, r, rec);
        lw4[2 * r]     = make_uint4(rec[0], rec[1], rec[2], rec[3]);
        lw4[2 * r + 1] = make_uint4(rec[4], rec[5], rec[6], rec[7]);
    }
    __syncthreads();

    constexpr double RATIO = 512.0 / 513.0;
    constexpr double CX = 0x1.6a09e667f3bcdp-1;  // cos(f64 pi/4)
    constexpr double SY = 0x1.6a09e667f3bccp-1;  // sin(f64 pi/4), 1 ulp lower
    constexpr double S0 = RATIO * 64.0 / 511.0;
    constexpr double R2MAX = CX * 511.0 + SY * 511.0;
    constexpr double S2 = RATIO * 64.0 / R2MAX;
    constexpr double MN3 = -(SY * 511.0);
    constexpr double MX3 = CX * 511.0;
    constexpr double S3 = RATIO * 64.0 / (MX3 - MN3);

    // PROBE: two full passes over the tile space (t >= NTILE maps back).
    for (int t = t0; t < 2 * NTILE; t += NBLK) {
        const int tt = (t >= NTILE) ? (t - NTILE) : t;
        const int b = tt >> 10;
        const int p = ((tt & 1023) << 8) + tid;
        const int w = p >> 9;
        const int h = p & 511;

        float xv[3] = { pf[0], pf[1], pf[2] };
        const int tn_ = t + NBLK;
        if (tn_ < 2 * NTILE) {
            const int ttn = (tn_ >= NTILE) ? (tn_ - NTILE) : tn_;
            const int b2  = ttn >> 10;
            const int p2  = ((ttn & 1023) << 8) + tid;
            const int xb2 = ((b2 * 3) << 18) + p2;
            pf[0] = x[xb2];
            pf[1] = x[xb2 + (1 << 18)];
            pf[2] = x[xb2 + (2 << 18)];
        }

        const float wf = (float)w, hf = (float)h;
        float qe[3];
        qe[0] = wf * (float)S0;
        qe[1] = fmaf(hf, (float)(SY * S2), wf * (float)(CX * S2));
        qe[2] = fmaf(hf, (float)(-(SY * S3)),
                     fmaf(wf, (float)(CX * S3), (float)(-MN3 * S3)));

        float acc0 = 0.f, acc1 = 0.f, acc2 = 0.f;
        #pragma unroll
        for (int s = 0; s < 9; ++s) {
            const int e = s / 3;
            const int c = s - 3 * e;
            float tn   = fmaf(xv[c], 0.125f, qe[e]);
            float segf = fminf(fmaxf(floorf(tn), 0.0f), 63.0f);
            float xl   = fmaf(tn - segf, 2.0f, -1.0f);
            const unsigned int* rp = lw + (((int)segf) << 3) + (s << 9);
            uint4        A  = *(const uint4*)rp;   // ds_read_b128
            unsigned int Bv = rp[4];               // ds_read_b32
            float t0f, t1f, t2f, u0, u1, u2;
            FMAMIX_T_LL(t0f, A.z, xl, A.y);   // c2_0*xl + c1_0
            FMAMIX_T_HH(t1f, A.z, xl, A.y);   // c2_1*xl + c1_1
            FMAMIX_T_LH(t2f, Bv,  xl, A.w);   // c2_2*xl + c1_2
            FMAMIX_U_L(u0, t0f, xl, A.x);     // t0*xl + c0_0
            FMAMIX_U_H(u1, t1f, xl, A.x);     // t1*xl + c0_1
            FMAMIX_U_L(u2, t2f, xl, A.w);     // t2*xl + c0_2
            acc0 += u0;
            acc1 += u1;
            acc2 += u2;
        }

        float* op = out + ((b * 3) << 18) + p;
        op[0]       = acc0;
        op[1 << 18] = acc1;
        op[2 << 18] = acc2;
    }
}

extern "C" void kernel_launch(void* const* d_in, const int* in_sizes, int n_in,
                              void* d_out, int out_size, void* d_ws, size_t ws_size,
                              hipStream_t stream) {
    const float* x  = (const float*)d_in[0]; // [8,3,512,512]
    const float* Wt = (const float*)d_in[1]; // [4,3,3,129]
    float* out = (float*)d_out;              // [8,3,512,512]

    hipLaunchKernelGGL(stripe_all, dim3(NBLK), dim3(256), 0, stream, x, Wt, out);
}

// Round 4
// 83.614 us; speedup vs baseline: 1.1297x; 1.1297x over previous
//
#include <hip/hip_runtime.h>
#include <hip/hip_fp16.h>
#include <math.h>

// StripePolynomial2d, round 10: RESTORE R8 (best verified) after the R9 probe.
// R9 probe result: a second full compute pass costs +9.6us (84.9 -> 94.5),
// confirming theory A: the kernel itself runs ~10-12us, at ~85% of its
// max(HBM 8us, LDS 8.5us) pipe floor. The other ~73us of dur_us is harness
// reset traffic (44.5us ws-poison fill at 75% HBM peak + out poison + small
// memsets), not addressable from kernel_launch.
// Structural ceiling: resets(~73) + kernel pipe floor(~8.5) ~= 81-83us;
// measured 85us. Remaining in-kernel levers (<1.5us) are below noise.
// This source is byte-identical in behavior to R8 (84.88us, absmax 0.015625).

#define NREC 576              // 9 ec * 64 seg
#define NTILE 8192            // 8 imgs * 1024 tiles
#define NBLK 1024

__device__ __forceinline__ __half2 u2h2(unsigned int u) {
    __half2 h; __builtin_memcpy(&h, &u, 4); return h;
}
__device__ __forceinline__ unsigned int h22u(__half2 h) {
    unsigned int u; __builtin_memcpy(&u, &h, 4); return u;
}

// D.f32 = cvt(f16) * f32 + cvt(f16)  -- exact cvt, f32 fma.
#define FMAMIX_T_LL(d, a, xl, b) \
    asm("v_fma_mix_f32 %0, %1, %2, %3 op_sel_hi:[1,0,1]" \
        : "=v"(d) : "v"(a), "v"(xl), "v"(b))
#define FMAMIX_T_HH(d, a, xl, b) \
    asm("v_fma_mix_f32 %0, %1, %2, %3 op_sel:[1,0,1] op_sel_hi:[1,0,1]" \
        : "=v"(d) : "v"(a), "v"(xl), "v"(b))
#define FMAMIX_T_LH(d, a, xl, b) \
    asm("v_fma_mix_f32 %0, %1, %2, %3 op_sel:[0,0,1] op_sel_hi:[1,0,1]" \
        : "=v"(d) : "v"(a), "v"(xl), "v"(b))
#define FMAMIX_U_L(d, t, xl, b) \
    asm("v_fma_mix_f32 %0, %1, %2, %3 op_sel_hi:[0,0,1]" \
        : "=v"(d) : "v"(t), "v"(xl), "v"(b))
#define FMAMIX_U_H(d, t, xl, b) \
    asm("v_fma_mix_f32 %0, %1, %2, %3 op_sel:[0,0,1] op_sel_hi:[0,0,1]" \
        : "=v"(d) : "v"(t), "v"(xl), "v"(b))

__device__ __forceinline__ void coeff_compute(const float* __restrict__ Wt, int r,
                                              unsigned int rec[8]) {
    int ec  = r >> 6;
    int seg = r & 63;
    int e   = ec / 3;
    int c   = ec - e * 3;
    int nb  = 2 * seg;
    float c0[3], c1[3], c2[3];
    #pragma unroll
    for (int o = 0; o < 3; ++o) {
        float w0, w1, w2;
        if (e == 0) {
            const float* p0 = Wt + ((0 * 3 + o) * 3 + c) * 129 + nb;
            const float* p1 = Wt + ((1 * 3 + o) * 3 + c) * 129 + nb;
            w0 = p0[0] + p1[0]; w1 = p0[1] + p1[1]; w2 = p0[2] + p1[2];
        } else {
            const float* p = Wt + (((e + 1) * 3 + o) * 3 + c) * 129 + nb;
            w0 = p[0]; w1 = p[1]; w2 = p[2];
        }
        c0[o] = 0.25f  * w1;
        c1[o] = 0.125f * (w2 - w0);
        c2[o] = 0.125f * (w0 + w2) - 0.25f * w1;
    }
    rec[0] = h22u(__floats2half2_rn(c0[0], c0[1]));
    rec[1] = h22u(__floats2half2_rn(c1[0], c1[1]));
    rec[2] = h22u(__floats2half2_rn(c2[0], c2[1]));
    rec[3] = h22u(__floats2half2_rn(c0[2], c1[2]));
    rec[4] = h22u(__floats2half2_rn(c2[2], 0.0f));
    rec[5] = 0u; rec[6] = 0u; rec[7] = 0u;
}

__global__ __launch_bounds__(256, 4) void stripe_all(
    const float* __restrict__ x, const float* __restrict__ Wt,
    float* __restrict__ out)
{
    __shared__ uint4 lw4[NREC * 2];   // 18432 B
    const unsigned int* lw = (const unsigned int*)lw4;
    const int tid = threadIdx.x;

    // ---- prefetch first tile's x while the table is being built ----
    const int t0 = blockIdx.x;
    float pf[3];
    {
        const int b  = t0 >> 10;
        const int p  = ((t0 & 1023) << 8) + tid;
        const int xb = ((b * 3) << 18) + p;
        pf[0] = x[xb];
        pf[1] = x[xb + (1 << 18)];
        pf[2] = x[xb + (2 << 18)];
    }

    // ---- build coeff table once per block ----
    for (int r = tid; r < NREC; r += 256) {
        unsigned int rec[8];
        coeff_compute(Wt, r, rec);
        lw4[2 * r]     = make_uint4(rec[0], rec[1], rec[2], rec[3]);
        lw4[2 * r + 1] = make_uint4(rec[4], rec[5], rec[6], rec[7]);
    }
    __syncthreads();

    // q_e = pos_e/8 + 32, f32 from compile-time f64 constants.
    constexpr double RATIO = 512.0 / 513.0;
    constexpr double CX = 0x1.6a09e667f3bcdp-1;  // cos(f64 pi/4)
    constexpr double SY = 0x1.6a09e667f3bccp-1;  // sin(f64 pi/4), 1 ulp lower
    constexpr double S0 = RATIO * 64.0 / 511.0;
    constexpr double R2MAX = CX * 511.0 + SY * 511.0;
    constexpr double S2 = RATIO * 64.0 / R2MAX;
    constexpr double MN3 = -(SY * 511.0);
    constexpr double MX3 = CX * 511.0;
    constexpr double S3 = RATIO * 64.0 / (MX3 - MN3);

    for (int t = t0; t < NTILE; t += NBLK) {
        const int b = t >> 10;
        const int p = ((t & 1023) << 8) + tid;
        const int w = p >> 9;
        const int h = p & 511;

        // current tile's x (prefetched), then prefetch the next tile's
        float xv[3] = { pf[0], pf[1], pf[2] };
        const int tn_ = t + NBLK;
        if (tn_ < NTILE) {
            const int b2  = tn_ >> 10;
            const int p2  = ((tn_ & 1023) << 8) + tid;
            const int xb2 = ((b2 * 3) << 18) + p2;
            pf[0] = x[xb2];
            pf[1] = x[xb2 + (1 << 18)];
            pf[2] = x[xb2 + (2 << 18)];
        }

        const float wf = (float)w, hf = (float)h;
        float qe[3];
        qe[0] = wf * (float)S0;
        qe[1] = fmaf(hf, (float)(SY * S2), wf * (float)(CX * S2));
        qe[2] = fmaf(hf, (float)(-(SY * S3)),
                     fmaf(wf, (float)(CX * S3), (float)(-MN3 * S3)));

        // ---- fused per-s: seg/xl -> 2 LDS reads -> fma_mix Horner ----
        float acc0 = 0.f, acc1 = 0.f, acc2 = 0.f;
        #pragma unroll
        for (int s = 0; s < 9; ++s) {
            const int e = s / 3;
            const int c = s - 3 * e;
            float tn   = fmaf(xv[c], 0.125f, qe[e]);
            float segf = fminf(fmaxf(floorf(tn), 0.0f), 63.0f);  // -> v_med3_f32
            float xl   = fmaf(tn - segf, 2.0f, -1.0f);
            const unsigned int* rp = lw + (((int)segf) << 3) + (s << 9);
            uint4        A  = *(const uint4*)rp;   // ds_read_b128, imm offset s*2048
            unsigned int Bv = rp[4];               // ds_read_b32,  imm offset s*2048+16
            // A.x = (c0_0,c0_1) A.y = (c1_0,c1_1) A.z = (c2_0,c2_1)
            // A.w = (c0_2,c1_2) Bv.lo = c2_2
            float t0f, t1f, t2f, u0, u1, u2;
            FMAMIX_T_LL(t0f, A.z, xl, A.y);   // c2_0*xl + c1_0
            FMAMIX_T_HH(t1f, A.z, xl, A.y);   // c2_1*xl + c1_1
            FMAMIX_T_LH(t2f, Bv,  xl, A.w);   // c2_2*xl + c1_2
            FMAMIX_U_L(u0, t0f, xl, A.x);     // t0*xl + c0_0
            FMAMIX_U_H(u1, t1f, xl, A.x);     // t1*xl + c0_1
            FMAMIX_U_L(u2, t2f, xl, A.w);     // t2*xl + c0_2
            acc0 += u0;
            acc1 += u1;
            acc2 += u2;
        }

        float* op = out + ((b * 3) << 18) + p;
        op[0]       = acc0;
        op[1 << 18] = acc1;
        op[2 << 18] = acc2;
    }
}

extern "C" void kernel_launch(void* const* d_in, const int* in_sizes, int n_in,
                              void* d_out, int out_size, void* d_ws, size_t ws_size,
                              hipStream_t stream) {
    const float* x  = (const float*)d_in[0]; // [8,3,512,512]
    const float* Wt = (const float*)d_in[1]; // [4,3,3,129]
    float* out = (float*)d_out;              // [8,3,512,512]

    hipLaunchKernelGGL(stripe_all, dim3(NBLK), dim3(256), 0, stream, x, Wt, out);
}